// Round 7
// baseline (56.375 us; speedup 1.0000x reference)
//
#include <hip/hip_runtime.h>
#include <hip/hip_bf16.h>

#define BB 64
#define NN 96
#define FF 16
#define HH 128
#define KK 64
#define LL 3
#define CUTOFF_F 10.0f
#define GAMMA_F 10.0f

#define WT_BLOCKS 99          // 3 layers * 33 blocks (2 rows of W3 each, 65 rows/layer)
#define CNT_BLOCKS BB

// ---------------------------------------------------------------------------
// pre_kernel:
//   [0,99):   rows {2i,2i+1} of W2[l]=Wrbf@Wpair (row 64 = bias row) staged in
//             LDS, then W3 rows = W2row@Wa1 (row 64 -> c3).
//   [99,163): cnt[b] = #valid atoms; zero out[b] (atomic target in chain)
// ---------------------------------------------------------------------------
__global__ __launch_bounds__(256) void pre_kernel(
    const float* __restrict__ Wrbf, const float* __restrict__ brbf,
    const float* __restrict__ Wpair, const float* __restrict__ bpair,
    const float* __restrict__ Wa1,
    const int* __restrict__ batch,
    float* __restrict__ W3, float* __restrict__ c3,
    float* __restrict__ cnt, float* __restrict__ out)
{
    const int bid = blockIdx.x;
    const int tid = threadIdx.x;
    if (bid < WT_BLOCKS) {
        __shared__ float sW2[2][HH];
        const int l    = bid / 33;
        const int r0   = (bid % 33) * 2;
        const int half = tid >> 7;
        const int h    = tid & 127;
        const int kk   = r0 + half;       // 0..65 (65 inactive)
        const bool active = (kk <= KK);
        if (active) {
            const float* Wp = Wpair + l * HH * HH + h;
            const float* arow;
            float acc;
            if (kk < KK) { arow = Wrbf + (l * KK + kk) * HH; acc = 0.f; }
            else         { arow = brbf + l * HH;             acc = bpair[l * HH + h]; }
            #pragma unroll 8
            for (int m = 0; m < HH; ++m) acc += arow[m] * Wp[m * HH];
            sW2[half][h] = acc;
        }
        __syncthreads();
        if (active) {
            const float* Wa = Wa1 + l * HH * HH + h;
            const float* row = sW2[half];
            float a3 = 0.f;
            #pragma unroll 8
            for (int m = 0; m < HH; ++m) a3 += row[m] * Wa[m * HH];
            if (kk < KK) W3[(l * KK + kk) * HH + h] = a3;
            else         c3[l * HH + h] = a3;
        }
    } else {
        int b = bid - WT_BLOCKS;
        __shared__ int c[4];
        bool v = (tid < NN) && (batch[b * NN + tid] != -1);
        unsigned long long m = __ballot(v);
        if ((tid & 63) == 0) c[tid >> 6] = __popcll(m);
        __syncthreads();
        if (tid == 0) {
            cnt[b] = (float)(c[0] + c[1] + c[2] + c[3]);
            out[b] = 0.f;                 // zero the atomic target each call
        }
    }
}

// ---------------------------------------------------------------------------
// chain_kernel: fused S-compute + per-atom MLP chain, wide thread tiles.
// Block = 256 threads: q = tid&31 (channel quad: 4q..4q+3), g = tid>>5
// (atom triple: 3g..3g+2). AT=24 atoms/block, grid 256 = 1 block/CU.
// Per GEMM k-step: 1 b128 weight read + 1 b128 atom read -> 12 FMAs.
// Weights DMA'd into LDS ping-pong (2x32KB) one chunk ahead.
// ---------------------------------------------------------------------------
#define AT 24
#define SSW 36   // padded row width (floats): atom a of triple g at col 4g+a

typedef const __attribute__((address_space(1))) void* gp1_t;
typedef __attribute__((address_space(3))) void* lp3_t;

__device__ __forceinline__ void stage32k(const float* g, float* l, int tid)
{
    const int lane = tid & 63, wv = tid >> 6;
    #pragma unroll
    for (int j = 0; j < 8; ++j) {
        const int base = j * 256 + wv * 64;            // float4 units
        __builtin_amdgcn_global_load_lds((gp1_t)(g + (size_t)(base + lane) * 4),
                                         (lp3_t)(l + (size_t)base * 4), 16, 0, 0);
    }
}

#define VMCNT0() asm volatile("s_waitcnt vmcnt(0)" ::: "memory")

__device__ __forceinline__ float silu1(float v) { return v / (1.f + __expf(-v)); }

// acc[12]: index a*4+c (a=atom 0..2, c=channel 0..3)
#define FMA12(ACC, W4, T4)                                              \
    do {                                                                \
        ACC[0] += (W4).x * (T4).x; ACC[1] += (W4).y * (T4).x;           \
        ACC[2] += (W4).z * (T4).x; ACC[3] += (W4).w * (T4).x;           \
        ACC[4] += (W4).x * (T4).y; ACC[5] += (W4).y * (T4).y;           \
        ACC[6] += (W4).z * (T4).y; ACC[7] += (W4).w * (T4).y;           \
        ACC[8] += (W4).x * (T4).z; ACC[9] += (W4).y * (T4).z;           \
        ACC[10]+= (W4).z * (T4).z; ACC[11]+= (W4).w * (T4).z;           \
    } while (0)

__global__ __launch_bounds__(256) void chain_kernel(
    const float* __restrict__ X, const float* __restrict__ R,
    const float* __restrict__ We, const float* __restrict__ be,
    const float* __restrict__ ba1, const float* __restrict__ Wa2,
    const float* __restrict__ ba2, const float* __restrict__ Wo1,
    const float* __restrict__ bo1, const float* __restrict__ Wo2,
    const float* __restrict__ bo2, const float* __restrict__ W3,
    const float* __restrict__ c3, const float* __restrict__ cnt,
    float* __restrict__ out)
{
    __shared__ __align__(16) float sS[KK][SSW];      // 9.2 KB (S^T)
    __shared__ __align__(16) float tb[HH][SSW];      // 18.4 KB (t/h staging; sD+sRf early)
    __shared__ __align__(16) float sX[FF][SSW];      // 2.3 KB
    __shared__ __align__(16) float wb[2][KK * HH];   // 64 KB weight ping-pong
    __shared__ float po[AT];

    const int tid = threadIdx.x;
    const int q   = tid & 31;            // channel quad
    const int g   = tid >> 5;            // atom triple (0..7)
    const int c0  = 4 * q;
    const int g4  = 4 * g;
    const int a0  = blockIdx.x * AT;     // 96 % 24 == 0 -> block within one molecule
    const int b   = a0 / NN;
    const int lbase = a0 - b * NN;       // molecule-local first atom
    const float cb = cnt[b];
    const int nv  = (int)cb;             // valid atoms are prefix 0..nv-1 (local)

    // scratch aliased into tb (dead before first tb write)
    float* sD  = &tb[0][0];              // AT*NN = 2304 floats: distances
    float* sRf = sD + AT * NN;           // 288 floats: molecule R

    // ---- issue weight DMAs for layer 0 ----
    stage32k(W3, wb[0], tid);            // W3[0]
    stage32k(Wa2, wb[1], tid);           // Wa2[0] rows 0..63

    // ---- stage molecule R, X^T ----
    for (int t = tid; t < NN * 3; t += 256) sRf[t] = R[b * NN * 3 + t];
    for (int t = tid; t < AT * FF; t += 256) {
        int a = t >> 4, f = t & 15;
        sX[f][(a / 3) * 4 + a % 3] = X[(a0 + a) * FF + f];
    }
    __syncthreads();

    // ---- phase 1: distance table D[j][i] ----
    for (int e = tid; e < AT * NN; e += 256) {
        int j = e / NN, i = e - j * NN;
        float dx = sRf[i * 3 + 0] - sRf[(lbase + j) * 3 + 0];
        float dy = sRf[i * 3 + 1] - sRf[(lbase + j) * 3 + 1];
        float dz = sRf[i * 3 + 2] - sRf[(lbase + j) * 3 + 2];
        sD[e] = sqrtf(dx * dx + dy * dy + dz * dz);
    }
    __syncthreads();

    // ---- phase 2: sS[k][col(j)] = sum_{i<nv} exp(-g*(D[j][i]-ck)^2) ----
    {
        const int k  = tid & 63;
        const int wv = tid >> 6;
        const float ck = (float)k * (CUTOFF_F / (float)(KK - 1));
        #pragma unroll
        for (int r = 0; r < 6; ++r) {
            int j = wv * 6 + r;          // wave-uniform
            int col = (j / 3) * 4 + j % 3;
            if (lbase + j >= nv) { sS[k][col] = 0.f; continue; }
            const float* Dr = sD + j * NN;
            float acc = 0.f;
            for (int i = 0; i < nv; ++i) {
                float u = Dr[i] - ck;
                acc += __expf(-GAMMA_F * u * u);
            }
            sS[k][col] = acc;
        }
    }

    // ---- embedding: h = X@We + be ----
    float h[12];
    {
        float acc[12] = {0,0,0,0,0,0,0,0,0,0,0,0};
        #pragma unroll
        for (int f = 0; f < FF; ++f) {
            float4 w4 = *(const float4*)&We[f * HH + c0];
            float4 x4 = *(const float4*)&sX[f][g4];
            FMA12(acc, w4, x4);
        }
        float4 be4 = *(const float4*)&be[c0];
        h[0]=acc[0]+be4.x; h[1]=acc[1]+be4.y; h[2] =acc[2] +be4.z; h[3] =acc[3] +be4.w;
        h[4]=acc[4]+be4.x; h[5]=acc[5]+be4.y; h[6] =acc[6] +be4.z; h[7] =acc[7] +be4.w;
        h[8]=acc[8]+be4.x; h[9]=acc[9]+be4.y; h[10]=acc[10]+be4.z; h[11]=acc[11]+be4.w;
    }

    VMCNT0();
    __syncthreads();   // sync0: wb ready; sS visible; sD/sRf dead

    // ---- layers ----
    for (int l = 0; l < LL; ++l) {
        const int P = l & 1, Q = P ^ 1;

        // GEMM1: acc = S @ W3[l]   (wb[P], sS)
        float acc[12] = {0,0,0,0,0,0,0,0,0,0,0,0};
        {
            const float* wp = &wb[P][c0];
            const float* sp = &sS[0][g4];
            #pragma unroll 8
            for (int k = 0; k < KK; ++k) {
                float4 w4 = *(const float4*)(wp + k * HH);
                float4 t4 = *(const float4*)(sp + k * SSW);
                FMA12(acc, w4, t4);
            }
        }
        float4 c34  = *(const float4*)&c3[l * HH + c0];
        float4 ba14 = *(const float4*)&ba1[l * HH + c0];
        float s[12];
        s[0] = silu1(acc[0] + cb*c34.x + ba14.x); s[1] = silu1(acc[1] + cb*c34.y + ba14.y);
        s[2] = silu1(acc[2] + cb*c34.z + ba14.z); s[3] = silu1(acc[3] + cb*c34.w + ba14.w);
        s[4] = silu1(acc[4] + cb*c34.x + ba14.x); s[5] = silu1(acc[5] + cb*c34.y + ba14.y);
        s[6] = silu1(acc[6] + cb*c34.z + ba14.z); s[7] = silu1(acc[7] + cb*c34.w + ba14.w);
        s[8] = silu1(acc[8] + cb*c34.x + ba14.x); s[9] = silu1(acc[9] + cb*c34.y + ba14.y);
        s[10]= silu1(acc[10]+ cb*c34.z + ba14.z); s[11]= silu1(acc[11]+ cb*c34.w + ba14.w);
        // write t: rows = channels 4q+c, cols = atoms g4+a (pad .w)
        *(float4*)&tb[c0 + 0][g4] = make_float4(s[0], s[4], s[8],  0.f);
        *(float4*)&tb[c0 + 1][g4] = make_float4(s[1], s[5], s[9],  0.f);
        *(float4*)&tb[c0 + 2][g4] = make_float4(s[2], s[6], s[10], 0.f);
        *(float4*)&tb[c0 + 3][g4] = make_float4(s[3], s[7], s[11], 0.f);
        VMCNT0();
        __syncthreads();   // sync1: wb[P] free, tb visible, wb[Q] (Wa2a) ready
        stage32k(Wa2 + l * HH * HH + 64 * HH, wb[P], tid);   // Wa2[l] rows 64..127

        // GEMM2a: m = 0..63 from wb[Q]
        float acc2[12] = {0,0,0,0,0,0,0,0,0,0,0,0};
        {
            const float* wq = &wb[Q][c0];
            const float* tp = &tb[0][g4];
            #pragma unroll 8
            for (int m = 0; m < 64; ++m) {
                float4 w4 = *(const float4*)(wq + m * HH);
                float4 t4 = *(const float4*)(tp + m * SSW);
                FMA12(acc2, w4, t4);
            }
        }
        VMCNT0();
        __syncthreads();   // sync2: wb[Q] free, wb[P] (Wa2b) ready
        stage32k((l < LL - 1) ? (W3 + (l + 1) * KK * HH) : Wo1, wb[Q], tid);

        // GEMM2b: m = 64..127 from wb[P]
        {
            const float* wp = &wb[P][c0];
            const float* tp = &tb[64][g4];
            #pragma unroll 8
            for (int m = 0; m < 64; ++m) {
                float4 w4 = *(const float4*)(wp + m * HH);
                float4 t4 = *(const float4*)(tp + m * SSW);
                FMA12(acc2, w4, t4);
            }
        }
        float4 ba24 = *(const float4*)&ba2[l * HH + c0];
        h[0] += acc2[0] + ba24.x; h[1] += acc2[1] + ba24.y;
        h[2] += acc2[2] + ba24.z; h[3] += acc2[3] + ba24.w;
        h[4] += acc2[4] + ba24.x; h[5] += acc2[5] + ba24.y;
        h[6] += acc2[6] + ba24.z; h[7] += acc2[7] + ba24.w;
        h[8] += acc2[8] + ba24.x; h[9] += acc2[9] + ba24.y;
        h[10]+= acc2[10]+ ba24.z; h[11]+= acc2[11]+ ba24.w;
        VMCNT0();
        __syncthreads();   // sync3: wb[P] free, wb[Q] (next W3 / Wo1a) ready, tb free
        stage32k((l < LL - 1) ? (Wa2 + (l + 1) * HH * HH) : (Wo1 + 64 * HH), wb[P], tid);
    }
    // after loop: wb[1] = Wo1 rows 0..63, wb[0] = Wo1 rows 64..127

    // ---- output head ----
    *(float4*)&tb[c0 + 0][g4] = make_float4(h[0], h[4], h[8],  0.f);
    *(float4*)&tb[c0 + 1][g4] = make_float4(h[1], h[5], h[9],  0.f);
    *(float4*)&tb[c0 + 2][g4] = make_float4(h[2], h[6], h[10], 0.f);
    *(float4*)&tb[c0 + 3][g4] = make_float4(h[3], h[7], h[11], 0.f);
    VMCNT0();
    __syncthreads();   // sync4: tb visible, both Wo1 chunks ready

    float acc[12] = {0,0,0,0,0,0,0,0,0,0,0,0};
    {
        const float* wq = &wb[1][c0];
        const float* tp = &tb[0][g4];
        #pragma unroll 8
        for (int m = 0; m < 64; ++m) {
            float4 w4 = *(const float4*)(wq + m * HH);
            float4 t4 = *(const float4*)(tp + m * SSW);
            FMA12(acc, w4, t4);
        }
        const float* wp = &wb[0][c0];
        const float* tp2 = &tb[64][g4];
        #pragma unroll 8
        for (int m = 0; m < 64; ++m) {
            float4 w4 = *(const float4*)(wp + m * HH);
            float4 t4 = *(const float4*)(tp2 + m * SSW);
            FMA12(acc, w4, t4);
        }
    }
    float4 bo14 = *(const float4*)&bo1[c0];
    float4 wo24 = *(const float4*)&Wo2[c0];
    float p[3];
    #pragma unroll
    for (int a = 0; a < 3; ++a) {
        p[a] = silu1(acc[a*4+0] + bo14.x) * wo24.x
             + silu1(acc[a*4+1] + bo14.y) * wo24.y
             + silu1(acc[a*4+2] + bo14.z) * wo24.z
             + silu1(acc[a*4+3] + bo14.w) * wo24.w;
    }
    // reduce over the 32 q-lanes within each half-wave (g constant per half)
    #pragma unroll
    for (int a = 0; a < 3; ++a) {
        float r = p[a];
        r += __shfl_down(r, 16); r += __shfl_down(r, 8);
        r += __shfl_down(r, 4);  r += __shfl_down(r, 2);
        r += __shfl_down(r, 1);
        p[a] = r;
    }
    {
        int lane = tid & 63;
        if (lane == 0 || lane == 32) {
            float bo2v = bo2[0];
            #pragma unroll
            for (int a = 0; a < 3; ++a) {
                int j = 3 * g + a;
                po[j] = (lbase + j < nv) ? (p[a] + bo2v) : 0.f;
            }
        }
    }
    __syncthreads();
    if (tid == 0) {
        float sum = 0.f;
        #pragma unroll
        for (int j = 0; j < AT; ++j) sum += po[j];
        atomicAdd(out + b, sum / cb);
    }
}

extern "C" void kernel_launch(void* const* d_in, const int* in_sizes, int n_in,
                              void* d_out, int out_size, void* d_ws, size_t ws_size,
                              hipStream_t stream) {
    const float* X     = (const float*)d_in[0];
    const float* R     = (const float*)d_in[1];
    const int*   batch = (const int*)  d_in[2];
    const float* We    = (const float*)d_in[3];
    const float* be    = (const float*)d_in[4];
    const float* Wrbf  = (const float*)d_in[5];
    const float* brbf  = (const float*)d_in[6];
    const float* Wpair = (const float*)d_in[7];
    const float* bpair = (const float*)d_in[8];
    const float* Wa1   = (const float*)d_in[9];
    const float* ba1   = (const float*)d_in[10];
    const float* Wa2   = (const float*)d_in[11];
    const float* ba2   = (const float*)d_in[12];
    const float* Wo1   = (const float*)d_in[13];
    const float* bo1   = (const float*)d_in[14];
    const float* Wo2   = (const float*)d_in[15];
    const float* bo2   = (const float*)d_in[16];

    float* w   = (float*)d_ws;
    float* W3  = w;                        // L*K*H = 24576
    float* c3  = W3 + LL * KK * HH;        // L*H   = 384
    float* cnt = c3 + LL * HH;             // B     = 64
    float* out = (float*)d_out;

    hipLaunchKernelGGL(pre_kernel, dim3(WT_BLOCKS + CNT_BLOCKS), dim3(256),
                       0, stream, Wrbf, brbf, Wpair, bpair, Wa1, batch,
                       W3, c3, cnt, out);
    hipLaunchKernelGGL(chain_kernel, dim3(BB * NN / AT), dim3(256), 0, stream,
                       X, R, We, be, ba1, Wa2, ba2, Wo1, bo1, Wo2, bo2,
                       W3, c3, cnt, out);
}